// Round 9
// baseline (2040.419 us; speedup 1.0000x reference)
//
#include <hip/hip_runtime.h>
#include <math.h>

#define S    612
#define SP   640          // padded state count (64 lanes x 10)
#define TT   8192
#define NB   32

// workspace layout (bytes)
#define WIN_OFF   0        // 640 float4 = 10240 B
#define IV_OFF    10240    // 4 floats
#define EMIS_OFF  16384    // 100*640 floats = 256000 B (pair-reordered)
#define OBS_OFF   272384   // 32*8192 ints = 1 MB  (16B aligned)

__global__ __launch_bounds__(256) void prep_tables(
    const float* __restrict__ tk, const float* __restrict__ ik,
    float* __restrict__ wIn2, float* __restrict__ Ivec)
{
    int i = blockIdx.x * 256 + threadIdx.x;
    if (i < S) {
        float l0 = tk[3*i], l1 = tk[3*i+1], l2 = tk[3*i+2], l3 = 1.0f;
        float m = fmaxf(fmaxf(l0, l1), fmaxf(l2, l3));
        float e0 = expf(l0-m), e1 = expf(l1-m), e2 = expf(l2-m), e3 = expf(l3-m);
        float inv = 1.0f / (e0+e1+e2+e3);
        wIn2[4*i + 0]              = e0*inv;
        wIn2[4*((i+1)%S) + 1]      = e1*inv;
        wIn2[4*((i+2)%S) + 2]      = e2*inv;
        wIn2[4*((i+3)%S) + 3]      = e3*inv;
    } else if (i < SP) {
        wIn2[4*i+0] = 0.f; wIn2[4*i+1] = 0.f; wIn2[4*i+2] = 0.f; wIn2[4*i+3] = 0.f;
    } else if (i == SP) {
        float l0 = ik[0], l1 = ik[1], l2 = ik[2], l3 = ik[3];
        float m = fmaxf(fmaxf(l0,l1), fmaxf(l2,l3));
        float e0 = expf(l0-m), e1 = expf(l1-m), e2 = expf(l2-m), e3 = expf(l3-m);
        float inv = 1.0f / (e0+e1+e2+e3);
        Ivec[0]=e0*inv; Ivec[1]=e1*inv; Ivec[2]=e2*inv; Ivec[3]=e3*inv;
    }
}

// emission table, stride-5 pair-reordered: row o holds, per lane l, five float2
// pairs (e[10l+j], e[10l+j+5]) at floats [o*SP + 10l + 2j {+1}]
__global__ __launch_bounds__(256) void prep_emis(
    const float* __restrict__ ek, float* __restrict__ emisP)
{
    int tid = blockIdx.x * 256 + threadIdx.x;       // tid = o*SP + s
    if (tid >= 100*SP) return;
    int s = tid % SP;
    int o = tid / SP;
    float val = 0.0f;
    if (s < S-1) {
        int c = o >> 2, l = o & 3;
        if (c == 0) {
            val = 0.25f;
        } else {
            const float* g = ek + s*96 + (c-1)*4;
            float a0=g[0], a1=g[1], a2=g[2], a3=g[3];
            float m = fmaxf(fmaxf(a0,a1), fmaxf(a2,a3));
            float x0=expf(a0-m), x1=expf(a1-m), x2=expf(a2-m), x3=expf(a3-m);
            float inv = 1.0f/(x0+x1+x2+x3);
            float sel = (l==0)?x0:(l==1)?x1:(l==2)?x2:x3;
            val = sel * inv;
        }
    }
    int ln = s / 10, j = s % 10;
    int pos = o*SP + ln*10 + ((j < 5) ? 2*j : 2*(j-5)+1);
    emisP[pos] = val;
}

__global__ __launch_bounds__(256) void extract_obs(
    const float* __restrict__ x, int* __restrict__ obs)
{
    int row  = blockIdx.x * 4 + (threadIdx.x >> 6);
    int lane = threadIdx.x & 63;
    if (row >= NB*TT) return;
    const float* r = x + (size_t)row * 101;
    float acc = r[lane] * (float)lane;
    if (lane < 37) acc += r[64 + lane] * (float)(64 + lane);
    #pragma unroll
    for (int m = 32; m >= 1; m >>= 1) acc += __shfl_xor(acc, m, 64);
    if (lane == 0) obs[row] = (int)(acc + 0.5f);
}

// lane-shift-up-by-1 via DPP wave_shr:1 (VALU pipe); lane 0 -> 0
__device__ __forceinline__ float dpp_up1(float x) {
    int xi = __builtin_bit_cast(int, x);
    int r = __builtin_amdgcn_update_dpp(0, xi, 0x138, 0xF, 0xF, true);
    return __builtin_bit_cast(float, r);
}
template<int CTRL>
__device__ __forceinline__ float dpp_add(float x) {
    int sh = __builtin_amdgcn_update_dpp(0, __builtin_bit_cast(int, x), CTRL, 0xF, 0xF, true);
    return x + __builtin_bit_cast(float, sh);
}
__device__ __forceinline__ float rdlanef(float x, int lane) {
    return __builtin_bit_cast(float, __builtin_amdgcn_readlane(__builtin_bit_cast(int, x), lane));
}
__device__ __forceinline__ int rdlanei(int x, int lane) {
    return __builtin_amdgcn_readlane(x, lane);
}
// packed f32 math (VOP3P, full-rate on CDNA): 2 FLOPs/lane/inst
__device__ __forceinline__ float2 pk_mul(float2 a, float2 b) {
    float2 d;
    asm("v_pk_mul_f32 %0, %1, %2" : "=v"(d) : "v"(a), "v"(b));
    return d;
}
__device__ __forceinline__ float2 pk_fma(float2 a, float2 b, float2 c) {
    float2 d;
    asm("v_pk_fma_f32 %0, %1, %2, %3" : "=v"(d) : "v"(a), "v"(b), "v"(c));
    return d;
}

// one HMM step on pair-array P (stride-5 pairs P[j]=(a_j,a_{j+5})); E0..E4 pairs
#define HMM_COREP_(P, E0,E1,E2,E3,E4)                                        \
  {                                                                          \
    float pm1 = dpp_up1(P[4].y);                                             \
    float pm2 = dpp_up1(P[3].y);                                             \
    float pm3 = dpp_up1(P[2].y);                                             \
    float v609 = rdlanef(P[4].y, 60);                                        \
    float v610 = rdlanef(P[0].x, 61);                                        \
    float v611 = rdlanef(P[1].x, 61);                                        \
    pm1 = isl0 ? v611 : pm1;                                                 \
    pm2 = isl0 ? v610 : pm2;                                                 \
    pm3 = isl0 ? v609 : pm3;                                                 \
    float2 B1 = make_float2(pm1, P[4].x);                                    \
    float2 B2 = make_float2(pm2, P[3].x);                                    \
    float2 B3 = make_float2(pm3, P[2].x);                                    \
    float2 c0 = pk_mul(P[0], W[0][0]);                                       \
    c0 = pk_fma(B1,   W[0][1], c0);                                          \
    c0 = pk_fma(B2,   W[0][2], c0);                                          \
    c0 = pk_fma(B3,   W[0][3], c0);                                          \
    float2 n0 = pk_mul(c0, (E0));                                            \
    float2 c1 = pk_mul(P[1], W[1][0]);                                       \
    c1 = pk_fma(P[0], W[1][1], c1);                                          \
    c1 = pk_fma(B1,   W[1][2], c1);                                          \
    c1 = pk_fma(B2,   W[1][3], c1);                                          \
    float2 n1 = pk_mul(c1, (E1));                                            \
    float2 c2 = pk_mul(P[2], W[2][0]);                                       \
    c2 = pk_fma(P[1], W[2][1], c2);                                          \
    c2 = pk_fma(P[0], W[2][2], c2);                                          \
    c2 = pk_fma(B1,   W[2][3], c2);                                          \
    float2 n2 = pk_mul(c2, (E2));                                            \
    float2 c3 = pk_mul(P[3], W[3][0]);                                       \
    c3 = pk_fma(P[2], W[3][1], c3);                                          \
    c3 = pk_fma(P[1], W[3][2], c3);                                          \
    c3 = pk_fma(P[0], W[3][3], c3);                                          \
    float2 n3 = pk_mul(c3, (E3));                                            \
    float2 c4 = pk_mul(P[4], W[4][0]);                                       \
    c4 = pk_fma(P[3], W[4][1], c4);                                          \
    c4 = pk_fma(P[2], W[4][2], c4);                                          \
    c4 = pk_fma(P[1], W[4][3], c4);                                          \
    float2 n4 = pk_mul(c4, (E4));                                            \
    P[0]=n0; P[1]=n1; P[2]=n2; P[3]=n3; P[4]=n4;                             \
  }

#define HMM_STEPP_(P, EBA, JB) HMM_COREP_(P, EBA[JB][0],EBA[JB][1],EBA[JB][2],EBA[JB][3],EBA[JB][4])

#define PREFETCH_(EBA, JB, OV)                                               \
  { int _oo = (OV);                                                          \
    const float2* _p = (const float2*)(emisP + _oo*SP + 10*l);               \
    EBA[JB][0]=_p[0]; EBA[JB][1]=_p[1]; EBA[JB][2]=_p[2];                    \
    EBA[JB][3]=_p[3]; EBA[JB][4]=_p[4]; }

#define LOCSUM_(P) (((P[0].x+P[0].y)+(P[1].x+P[1].y)) +                      \
                    ((P[2].x+P[2].y)+(P[3].x+P[3].y)) + (P[4].x+P[4].y))

// dual-batch 8-step renorm group: two independent recurrences interleaved
#define GROUP2(A0,A1,A2,A3,A4,A5,A6,A7, B0,B1v,B2v,B3v,B4,B5,B6,B7)          \
    HMM_STEPP_(pA, ebA, 0); HMM_STEPP_(pB, ebB, 0);                          \
    PREFETCH_(ebA, 0, A0);  PREFETCH_(ebB, 0, B0);                           \
    zlA = dpp_add<0x111>(zlA); zlB = dpp_add<0x111>(zlB);                    \
    HMM_STEPP_(pA, ebA, 1); HMM_STEPP_(pB, ebB, 1);                          \
    PREFETCH_(ebA, 1, A1);  PREFETCH_(ebB, 1, B1v);                          \
    zlA = dpp_add<0x112>(zlA); zlB = dpp_add<0x112>(zlB);                    \
    HMM_STEPP_(pA, ebA, 2); HMM_STEPP_(pB, ebB, 2);                          \
    PREFETCH_(ebA, 2, A2);  PREFETCH_(ebB, 2, B2v);                          \
    zlA = dpp_add<0x114>(zlA); zlB = dpp_add<0x114>(zlB);                    \
    HMM_STEPP_(pA, ebA, 3); HMM_STEPP_(pB, ebB, 3);                          \
    PREFETCH_(ebA, 3, A3);  PREFETCH_(ebB, 3, B3v);                          \
    zlA = dpp_add<0x118>(zlA); zlB = dpp_add<0x118>(zlB);                    \
    HMM_STEPP_(pA, ebA, 0); HMM_STEPP_(pB, ebB, 0);                          \
    PREFETCH_(ebA, 0, A4);  PREFETCH_(ebB, 0, B4);                           \
    zlA = dpp_add<0x142>(zlA); zlB = dpp_add<0x142>(zlB);                    \
    HMM_STEPP_(pA, ebA, 1); HMM_STEPP_(pB, ebB, 1);                          \
    PREFETCH_(ebA, 1, A5);  PREFETCH_(ebB, 1, B5);                           \
    zlA = dpp_add<0x143>(zlA); zlB = dpp_add<0x143>(zlB);                    \
    {                                                                        \
      float zA = rdlanef(zlA, 63), zB = rdlanef(zlB, 63);                    \
      float invA = __builtin_amdgcn_rcpf(zA);                                \
      float invB = __builtin_amdgcn_rcpf(zB);                                \
      float lgA = __logf(zA), lgB = __logf(zB);                              \
      HMM_STEPP_(pA, ebA, 2); HMM_STEPP_(pB, ebB, 2);                        \
      PREFETCH_(ebA, 2, A6);  PREFETCH_(ebB, 2, B6);                         \
      float2 ivA = make_float2(invA, invA), ivB = make_float2(invB, invB);   \
      float2 eA0 = pk_mul(ebA[3][0], ivA), eA1 = pk_mul(ebA[3][1], ivA);     \
      float2 eA2 = pk_mul(ebA[3][2], ivA), eA3 = pk_mul(ebA[3][3], ivA);     \
      float2 eA4 = pk_mul(ebA[3][4], ivA);                                   \
      float2 eB0 = pk_mul(ebB[3][0], ivB), eB1 = pk_mul(ebB[3][1], ivB);     \
      float2 eB2 = pk_mul(ebB[3][2], ivB), eB3 = pk_mul(ebB[3][3], ivB);     \
      float2 eB4 = pk_mul(ebB[3][4], ivB);                                   \
      HMM_COREP_(pA, eA0,eA1,eA2,eA3,eA4);                                   \
      HMM_COREP_(pB, eB0,eB1,eB2,eB3,eB4);                                   \
      PREFETCH_(ebA, 3, A7);  PREFETCH_(ebB, 3, B7);                         \
      llA += lgA; llB += lgB;                                                \
    }                                                                        \
    zlA = LOCSUM_(pA); zlB = LOCSUM_(pB);

// 16 blocks x 64 threads: one wave handles TWO batches (independent chains)
__global__ __launch_bounds__(64) void forward(
    const float* __restrict__ emisP, const float4* __restrict__ wIn2,
    const float* __restrict__ Ivec, const int* __restrict__ obs,
    float* __restrict__ out)
{
    const int l = threadIdx.x;
    const int bA = blockIdx.x * 2;
    const int bB = bA + 1;
    const bool isl0 = (l == 0);
    const int* obpA = obs + bA * TT;
    const int* obpB = obs + bB * TT;

    // shared per-lane weights, stride-5 pairs
    float2 W[5][4];
    {
        float4 w[10];
        #pragma unroll
        for (int k = 0; k < 10; ++k) w[k] = wIn2[10*l + k];
        #pragma unroll
        for (int j = 0; j < 5; ++j) {
            W[j][0] = make_float2(w[j].x, w[j+5].x);
            W[j][1] = make_float2(w[j].y, w[j+5].y);
            W[j][2] = make_float2(w[j].z, w[j+5].z);
            W[j][3] = make_float2(w[j].w, w[j+5].w);
        }
    }

    int ocurA = obpA[l], onxtA = obpA[64 + l];
    int ocurB = obpB[l], onxtB = obpB[64 + l];

    float2 pA[5], pB[5];
    float llA = 0.0f, llB = 0.0f;
    float2 ebA[4][5], ebB[4][5];

    // t = 0
    {
        int oA = rdlanei(ocurA, 0);
        const float2* ep = (const float2*)(emisP + oA*SP + 10*l);
        float2 e0=ep[0], e1=ep[1], e2=ep[2], e3=ep[3];
        pA[0] = make_float2(isl0 ? e0.x*Ivec[0] : 0.f, 0.f);
        pA[1] = make_float2(isl0 ? e1.x*Ivec[1] : 0.f, 0.f);
        pA[2] = make_float2(isl0 ? e2.x*Ivec[2] : 0.f, 0.f);
        pA[3] = make_float2(isl0 ? e3.x*Ivec[3] : 0.f, 0.f);
        pA[4] = make_float2(0.f, 0.f);
    }
    {
        int oB = rdlanei(ocurB, 0);
        const float2* ep = (const float2*)(emisP + oB*SP + 10*l);
        float2 e0=ep[0], e1=ep[1], e2=ep[2], e3=ep[3];
        pB[0] = make_float2(isl0 ? e0.x*Ivec[0] : 0.f, 0.f);
        pB[1] = make_float2(isl0 ? e1.x*Ivec[1] : 0.f, 0.f);
        pB[2] = make_float2(isl0 ? e2.x*Ivec[2] : 0.f, 0.f);
        pB[3] = make_float2(isl0 ? e3.x*Ivec[3] : 0.f, 0.f);
        pB[4] = make_float2(0.f, 0.f);
    }
    float zlA = LOCSUM_(pA);
    float zlB = LOCSUM_(pB);

    // initial emission buffers: steps 1..4
    PREFETCH_(ebA, 0, rdlanei(ocurA, 1));  PREFETCH_(ebB, 0, rdlanei(ocurB, 1));
    PREFETCH_(ebA, 1, rdlanei(ocurA, 2));  PREFETCH_(ebB, 1, rdlanei(ocurB, 2));
    PREFETCH_(ebA, 2, rdlanei(ocurA, 3));  PREFETCH_(ebB, 2, rdlanei(ocurB, 3));
    PREFETCH_(ebA, 3, rdlanei(ocurA, 4));  PREFETCH_(ebB, 3, rdlanei(ocurB, 4));

    // superblocks: steps 64k+1 .. 64k+64, k = 0..126  (t = 1..8128)
    for (int kk = 0; kk < 127; ++kk) {
        int src = 64*kk + 128 + l;
        if (src >= TT) src = 0;            // clamped tail (value unused)
        int ovNA = obpA[src];
        int ovNB = obpB[src];
        #pragma unroll 1
        for (int j = 0; j < 7; ++j) {
            int base = 8*j + 5;
            GROUP2(rdlanei(ocurA,base  ), rdlanei(ocurA,base+1),
                   rdlanei(ocurA,base+2), rdlanei(ocurA,base+3),
                   rdlanei(ocurA,base+4), rdlanei(ocurA,base+5),
                   rdlanei(ocurA,base+6), rdlanei(ocurA,base+7),
                   rdlanei(ocurB,base  ), rdlanei(ocurB,base+1),
                   rdlanei(ocurB,base+2), rdlanei(ocurB,base+3),
                   rdlanei(ocurB,base+4), rdlanei(ocurB,base+5),
                   rdlanei(ocurB,base+6), rdlanei(ocurB,base+7));
        }
        // j = 7 straddles the buffer boundary — compile-time lane indices
        GROUP2(rdlanei(ocurA,61), rdlanei(ocurA,62), rdlanei(ocurA,63),
               rdlanei(onxtA,0),  rdlanei(onxtA,1),  rdlanei(onxtA,2),
               rdlanei(onxtA,3),  rdlanei(onxtA,4),
               rdlanei(ocurB,61), rdlanei(ocurB,62), rdlanei(ocurB,63),
               rdlanei(onxtB,0),  rdlanei(onxtB,1),  rdlanei(onxtB,2),
               rdlanei(onxtB,3),  rdlanei(onxtB,4));
        ocurA = onxtA; onxtA = ovNA;
        ocurB = onxtB; onxtB = ovNB;
    }

    // epilogue groups: steps 8129..8184 (ocur covers [8128,8192))
    #pragma unroll 1
    for (int j = 0; j < 7; ++j) {
        int base = 8*j + 5;
        GROUP2(rdlanei(ocurA,base  ), rdlanei(ocurA,base+1),
               rdlanei(ocurA,base+2), rdlanei(ocurA,base+3),
               rdlanei(ocurA,base+4), rdlanei(ocurA,base+5),
               rdlanei(ocurA,base+6), rdlanei(ocurA,base+7),
               rdlanei(ocurB,base  ), rdlanei(ocurB,base+1),
               rdlanei(ocurB,base+2), rdlanei(ocurB,base+3),
               rdlanei(ocurB,base+4), rdlanei(ocurB,base+5),
               rdlanei(ocurB,base+6), rdlanei(ocurB,base+7));
    }

    // final steps 8185..8191 (no renorm; final sum captures residual scale)
    HMM_STEPP_(pA, ebA, 0); HMM_STEPP_(pB, ebB, 0);
    PREFETCH_(ebA, 0, rdlanei(ocurA,61)); PREFETCH_(ebB, 0, rdlanei(ocurB,61));
    HMM_STEPP_(pA, ebA, 1); HMM_STEPP_(pB, ebB, 1);
    PREFETCH_(ebA, 1, rdlanei(ocurA,62)); PREFETCH_(ebB, 1, rdlanei(ocurB,62));
    HMM_STEPP_(pA, ebA, 2); HMM_STEPP_(pB, ebB, 2);
    PREFETCH_(ebA, 2, rdlanei(ocurA,63)); PREFETCH_(ebB, 2, rdlanei(ocurB,63));
    HMM_STEPP_(pA, ebA, 3); HMM_STEPP_(pB, ebB, 3);
    HMM_STEPP_(pA, ebA, 0); HMM_STEPP_(pB, ebB, 0);
    HMM_STEPP_(pA, ebA, 1); HMM_STEPP_(pB, ebB, 1);
    HMM_STEPP_(pA, ebA, 2); HMM_STEPP_(pB, ebB, 2);

    {
        float zfA = LOCSUM_(pA);
        float zfB = LOCSUM_(pB);
        zfA = dpp_add<0x111>(zfA); zfB = dpp_add<0x111>(zfB);
        zfA = dpp_add<0x112>(zfA); zfB = dpp_add<0x112>(zfB);
        zfA = dpp_add<0x114>(zfA); zfB = dpp_add<0x114>(zfB);
        zfA = dpp_add<0x118>(zfA); zfB = dpp_add<0x118>(zfB);
        zfA = dpp_add<0x142>(zfA); zfB = dpp_add<0x142>(zfB);
        zfA = dpp_add<0x143>(zfA); zfB = dpp_add<0x143>(zfB);
        llA += __logf(rdlanef(zfA, 63));
        llB += __logf(rdlanef(zfB, 63));
    }
    if (isl0) { out[bA] = llA; out[bB] = llB; }
}

extern "C" void kernel_launch(void* const* d_in, const int* in_sizes, int n_in,
                              void* d_out, int out_size, void* d_ws, size_t ws_size,
                              hipStream_t stream)
{
    const float* x  = (const float*)d_in[0];   // inputs [32,8192,101]
    const float* ik = (const float*)d_in[1];   // init_kernel [4]
    const float* tk = (const float*)d_in[2];   // transition_kernel [1836]
    const float* ek = (const float*)d_in[3];   // emission_kernel [58656]
    float* out = (float*)d_out;

    char* ws = (char*)d_ws;
    float*  wIn2  = (float*)(ws + WIN_OFF);
    float*  Ivec  = (float*)(ws + IV_OFF);
    float*  emisP = (float*)(ws + EMIS_OFF);
    int*    obs   = (int*)(ws + OBS_OFF);

    hipLaunchKernelGGL(prep_tables, dim3(3), dim3(256), 0, stream, tk, ik, wIn2, Ivec);
    hipLaunchKernelGGL(prep_emis, dim3((100*SP + 255)/256), dim3(256), 0, stream, ek, emisP);
    hipLaunchKernelGGL(extract_obs, dim3((NB*TT + 3)/4), dim3(256), 0, stream, x, obs);
    hipLaunchKernelGGL(forward, dim3(NB/2), dim3(64), 0, stream,
                       emisP, (const float4*)wIn2, Ivec, obs, out);
}

// Round 10
// 970.266 us; speedup vs baseline: 2.1029x; 2.1029x over previous
//
#include <hip/hip_runtime.h>
#include <math.h>

#pragma clang fp contract(fast)

#define S    612
#define SP   640          // padded state count (64 lanes x 10)
#define TT   8192
#define NB   32

typedef float v2f __attribute__((ext_vector_type(2)));

// workspace layout (bytes)
#define WIN_OFF   0        // 640 float4 = 10240 B
#define IV_OFF    10240    // 4 floats
#define EMIS_OFF  16384    // 100*640 floats = 256000 B (pair-reordered)
#define OBS_OFF   272384   // 32*8192 ints = 1 MB  (16B aligned)

__global__ __launch_bounds__(256) void prep_tables(
    const float* __restrict__ tk, const float* __restrict__ ik,
    float* __restrict__ wIn2, float* __restrict__ Ivec)
{
    int i = blockIdx.x * 256 + threadIdx.x;
    if (i < S) {
        float l0 = tk[3*i], l1 = tk[3*i+1], l2 = tk[3*i+2], l3 = 1.0f;
        float m = fmaxf(fmaxf(l0, l1), fmaxf(l2, l3));
        float e0 = expf(l0-m), e1 = expf(l1-m), e2 = expf(l2-m), e3 = expf(l3-m);
        float inv = 1.0f / (e0+e1+e2+e3);
        wIn2[4*i + 0]              = e0*inv;
        wIn2[4*((i+1)%S) + 1]      = e1*inv;
        wIn2[4*((i+2)%S) + 2]      = e2*inv;
        wIn2[4*((i+3)%S) + 3]      = e3*inv;
    } else if (i < SP) {
        wIn2[4*i+0] = 0.f; wIn2[4*i+1] = 0.f; wIn2[4*i+2] = 0.f; wIn2[4*i+3] = 0.f;
    } else if (i == SP) {
        float l0 = ik[0], l1 = ik[1], l2 = ik[2], l3 = ik[3];
        float m = fmaxf(fmaxf(l0,l1), fmaxf(l2,l3));
        float e0 = expf(l0-m), e1 = expf(l1-m), e2 = expf(l2-m), e3 = expf(l3-m);
        float inv = 1.0f / (e0+e1+e2+e3);
        Ivec[0]=e0*inv; Ivec[1]=e1*inv; Ivec[2]=e2*inv; Ivec[3]=e3*inv;
    }
}

// emission table, stride-5 pair-reordered: row o holds, per lane l, five pairs
// (e[10l+j], e[10l+j+5]) at floats [o*SP + 10l + 2j {+1}]
__global__ __launch_bounds__(256) void prep_emis(
    const float* __restrict__ ek, float* __restrict__ emisP)
{
    int tid = blockIdx.x * 256 + threadIdx.x;       // tid = o*SP + s
    if (tid >= 100*SP) return;
    int s = tid % SP;
    int o = tid / SP;
    float val = 0.0f;
    if (s < S-1) {
        int c = o >> 2, l = o & 3;
        if (c == 0) {
            val = 0.25f;
        } else {
            const float* g = ek + s*96 + (c-1)*4;
            float a0=g[0], a1=g[1], a2=g[2], a3=g[3];
            float m = fmaxf(fmaxf(a0,a1), fmaxf(a2,a3));
            float x0=expf(a0-m), x1=expf(a1-m), x2=expf(a2-m), x3=expf(a3-m);
            float inv = 1.0f/(x0+x1+x2+x3);
            float sel = (l==0)?x0:(l==1)?x1:(l==2)?x2:x3;
            val = sel * inv;
        }
    }
    int ln = s / 10, j = s % 10;
    int pos = o*SP + ln*10 + ((j < 5) ? 2*j : 2*(j-5)+1);
    emisP[pos] = val;
}

__global__ __launch_bounds__(256) void extract_obs(
    const float* __restrict__ x, int* __restrict__ obs)
{
    int row  = blockIdx.x * 4 + (threadIdx.x >> 6);
    int lane = threadIdx.x & 63;
    if (row >= NB*TT) return;
    const float* r = x + (size_t)row * 101;
    float acc = r[lane] * (float)lane;
    if (lane < 37) acc += r[64 + lane] * (float)(64 + lane);
    #pragma unroll
    for (int m = 32; m >= 1; m >>= 1) acc += __shfl_xor(acc, m, 64);
    if (lane == 0) obs[row] = (int)(acc + 0.5f);
}

// lane-shift-up-by-1 via DPP wave_shr:1 (VALU pipe); lane 0 -> 0
__device__ __forceinline__ float dpp_up1(float x) {
    int xi = __builtin_bit_cast(int, x);
    int r = __builtin_amdgcn_update_dpp(0, xi, 0x138, 0xF, 0xF, true);
    return __builtin_bit_cast(float, r);
}
template<int CTRL>
__device__ __forceinline__ float dpp_add(float x) {
    int sh = __builtin_amdgcn_update_dpp(0, __builtin_bit_cast(int, x), CTRL, 0xF, 0xF, true);
    return x + __builtin_bit_cast(float, sh);
}
__device__ __forceinline__ float rdlanef(float x, int lane) {
    return __builtin_bit_cast(float, __builtin_amdgcn_readlane(__builtin_bit_cast(int, x), lane));
}
__device__ __forceinline__ int rdlanei(int x, int lane) {
    return __builtin_amdgcn_readlane(x, lane);
}

// one HMM step, stride-5 pairs p[j] = (a_j, a_{j+5}); E0..E4 emission pairs.
// Native ext_vector arithmetic — let LLVM pick v_pk_fma_f32 / scalar FMAs.
#define HMM_COREP(E0,E1,E2,E3,E4)                                            \
  {                                                                          \
    float pm1 = dpp_up1(p[4].y);                                             \
    float pm2 = dpp_up1(p[3].y);                                             \
    float pm3 = dpp_up1(p[2].y);                                             \
    float v609 = rdlanef(p[4].y, 60);                                        \
    float v610 = rdlanef(p[0].x, 61);                                        \
    float v611 = rdlanef(p[1].x, 61);                                        \
    pm1 = isl0 ? v611 : pm1;                                                 \
    pm2 = isl0 ? v610 : pm2;                                                 \
    pm3 = isl0 ? v609 : pm3;                                                 \
    v2f B1; B1.x = pm1; B1.y = p[4].x;                                       \
    v2f B2; B2.x = pm2; B2.y = p[3].x;                                       \
    v2f B3; B3.x = pm3; B3.y = p[2].x;                                       \
    v2f c0 = p[0]*W[0][0] + B1*W[0][1]   + B2*W[0][2]   + B3*W[0][3];        \
    v2f c1 = p[1]*W[1][0] + p[0]*W[1][1] + B1*W[1][2]   + B2*W[1][3];        \
    v2f c2 = p[2]*W[2][0] + p[1]*W[2][1] + p[0]*W[2][2] + B1*W[2][3];        \
    v2f c3 = p[3]*W[3][0] + p[2]*W[3][1] + p[1]*W[3][2] + p[0]*W[3][3];      \
    v2f c4 = p[4]*W[4][0] + p[3]*W[4][1] + p[2]*W[4][2] + p[1]*W[4][3];      \
    p[0] = c0*(E0); p[1] = c1*(E1); p[2] = c2*(E2);                          \
    p[3] = c3*(E3); p[4] = c4*(E4);                                          \
  }

#define HMM_STEPP(JB) HMM_COREP(eb[JB][0],eb[JB][1],eb[JB][2],eb[JB][3],eb[JB][4])

// refill rotating buffer JB with (pair-reordered) emission row for obs OV
#define PREFETCH(JB, OV)                                                     \
  { int _oo = (OV);                                                          \
    const v2f* _p = (const v2f*)(emisP + _oo*SP + 10*l);                     \
    eb[JB][0]=_p[0]; eb[JB][1]=_p[1]; eb[JB][2]=_p[2];                       \
    eb[JB][3]=_p[3]; eb[JB][4]=_p[4]; }

#define LOCSUM() (((p[0].x+p[0].y)+(p[1].x+p[1].y)) +                        \
                  ((p[2].x+p[2].y)+(p[3].x+p[3].y)) + (p[4].x+p[4].y))

// 8-step renorm group; z-reduction on the VALU pipe (DPP), one stage per step
#define GROUP(O0,O1,O2,O3,O4,O5,O6,O7)                                       \
    HMM_STEPP(0); PREFETCH(0, O0);                                           \
    zl = dpp_add<0x111>(zl);                                                 \
    HMM_STEPP(1); PREFETCH(1, O1);                                           \
    zl = dpp_add<0x112>(zl);                                                 \
    HMM_STEPP(2); PREFETCH(2, O2);                                           \
    zl = dpp_add<0x114>(zl);                                                 \
    HMM_STEPP(3); PREFETCH(3, O3);                                           \
    zl = dpp_add<0x118>(zl);                                                 \
    HMM_STEPP(0); PREFETCH(0, O4);                                           \
    zl = dpp_add<0x142>(zl);                                                 \
    HMM_STEPP(1); PREFETCH(1, O5);                                           \
    zl = dpp_add<0x143>(zl);                                                 \
    {                                                                        \
      float z   = rdlanef(zl, 63);                                           \
      float inv = __builtin_amdgcn_rcpf(z);                                  \
      float lg  = __logf(z);                                                 \
      HMM_STEPP(2); PREFETCH(2, O6);                                         \
      v2f ivP; ivP.x = inv; ivP.y = inv;                                     \
      v2f ep0 = eb[3][0]*ivP, ep1 = eb[3][1]*ivP, ep2 = eb[3][2]*ivP;        \
      v2f ep3 = eb[3][3]*ivP, ep4 = eb[3][4]*ivP;                            \
      HMM_COREP(ep0,ep1,ep2,ep3,ep4);                                        \
      PREFETCH(3, O7);                                                       \
      ll += lg;                                                              \
    }                                                                        \
    zl = LOCSUM();

// one wave per batch; no LDS; native packed-f32 main loop
__global__ __launch_bounds__(64) void forward(
    const float* __restrict__ emisP, const float4* __restrict__ wIn2,
    const float* __restrict__ Ivec, const int* __restrict__ obs,
    float* __restrict__ out)
{
    const int l = threadIdx.x;
    const int b = blockIdx.x;
    const bool isl0 = (l == 0);
    const int* obp = obs + b * TT;

    // load per-state incoming weights, then build stride-5 pairs
    v2f W[5][4];
    {
        float4 w[10];
        #pragma unroll
        for (int k = 0; k < 10; ++k) w[k] = wIn2[10*l + k];
        #pragma unroll
        for (int j = 0; j < 5; ++j) {
            W[j][0].x = w[j].x; W[j][0].y = w[j+5].x;
            W[j][1].x = w[j].y; W[j][1].y = w[j+5].y;
            W[j][2].x = w[j].z; W[j][2].y = w[j+5].z;
            W[j][3].x = w[j].w; W[j][3].y = w[j+5].w;
        }
    }

    // obs ring: lane l of ovA holds obs[64k + l], ovB holds obs[64k+64 + l]
    int ovA = obp[l];
    int ovB = obp[64 + l];

    v2f p[5];
    float ll = 0.0f;
    v2f eb[4][5];

    // t = 0: states 0..3 (lane 0, lo halves of pairs 0..3) get I*emission
    {
        int o0 = rdlanei(ovA, 0);
        const v2f* ep = (const v2f*)(emisP + o0*SP + 10*l);
        v2f e0=ep[0], e1=ep[1], e2=ep[2], e3=ep[3];
        p[0].x = isl0 ? e0.x*Ivec[0] : 0.f;  p[0].y = 0.f;
        p[1].x = isl0 ? e1.x*Ivec[1] : 0.f;  p[1].y = 0.f;
        p[2].x = isl0 ? e2.x*Ivec[2] : 0.f;  p[2].y = 0.f;
        p[3].x = isl0 ? e3.x*Ivec[3] : 0.f;  p[3].y = 0.f;
        p[4].x = 0.f; p[4].y = 0.f;
    }
    float zl = LOCSUM();   // z_0 partial; DPP tree runs inside first group

    // initial emission buffers: steps 1..4
    PREFETCH(0, rdlanei(ovA, 1));
    PREFETCH(1, rdlanei(ovA, 2));
    PREFETCH(2, rdlanei(ovA, 3));
    PREFETCH(3, rdlanei(ovA, 4));

    // superblocks: steps 64k+1 .. 64k+64, k = 0..126  (t = 1..8128)
    for (int kk = 0; kk < 127; ++kk) {
        int src = 64*kk + 128 + l;
        if (src >= TT) src = 0;            // clamped tail (value unused)
        int ovN = obp[src];
        #pragma unroll 1
        for (int j = 0; j < 7; ++j) {
            int base = 8*j + 5;
            GROUP(rdlanei(ovA,base  ), rdlanei(ovA,base+1),
                  rdlanei(ovA,base+2), rdlanei(ovA,base+3),
                  rdlanei(ovA,base+4), rdlanei(ovA,base+5),
                  rdlanei(ovA,base+6), rdlanei(ovA,base+7));
        }
        // j = 7 straddles the buffer boundary — compile-time lane indices
        GROUP(rdlanei(ovA,61), rdlanei(ovA,62), rdlanei(ovA,63),
              rdlanei(ovB,0),  rdlanei(ovB,1),  rdlanei(ovB,2),
              rdlanei(ovB,3),  rdlanei(ovB,4));
        ovA = ovB; ovB = ovN;
    }

    // epilogue groups: steps 8129..8184 (ovA covers [8128,8192))
    #pragma unroll 1
    for (int j = 0; j < 7; ++j) {
        int base = 8*j + 5;
        GROUP(rdlanei(ovA,base  ), rdlanei(ovA,base+1),
              rdlanei(ovA,base+2), rdlanei(ovA,base+3),
              rdlanei(ovA,base+4), rdlanei(ovA,base+5),
              rdlanei(ovA,base+6), rdlanei(ovA,base+7));
    }

    // final steps 8185..8191 (no renorm; final sum captures residual scale)
    HMM_STEPP(0); PREFETCH(0, rdlanei(ovA,61));
    HMM_STEPP(1); PREFETCH(1, rdlanei(ovA,62));
    HMM_STEPP(2); PREFETCH(2, rdlanei(ovA,63));
    HMM_STEPP(3);
    HMM_STEPP(0);
    HMM_STEPP(1);
    HMM_STEPP(2);

    {
        float zf = LOCSUM();
        zf = dpp_add<0x111>(zf);
        zf = dpp_add<0x112>(zf);
        zf = dpp_add<0x114>(zf);
        zf = dpp_add<0x118>(zf);
        zf = dpp_add<0x142>(zf);
        zf = dpp_add<0x143>(zf);
        ll += __logf(rdlanef(zf, 63));
    }
    if (isl0) out[b] = ll;
}

extern "C" void kernel_launch(void* const* d_in, const int* in_sizes, int n_in,
                              void* d_out, int out_size, void* d_ws, size_t ws_size,
                              hipStream_t stream)
{
    const float* x  = (const float*)d_in[0];   // inputs [32,8192,101]
    const float* ik = (const float*)d_in[1];   // init_kernel [4]
    const float* tk = (const float*)d_in[2];   // transition_kernel [1836]
    const float* ek = (const float*)d_in[3];   // emission_kernel [58656]
    float* out = (float*)d_out;

    char* ws = (char*)d_ws;
    float*  wIn2  = (float*)(ws + WIN_OFF);
    float*  Ivec  = (float*)(ws + IV_OFF);
    float*  emisP = (float*)(ws + EMIS_OFF);
    int*    obs   = (int*)(ws + OBS_OFF);

    hipLaunchKernelGGL(prep_tables, dim3(3), dim3(256), 0, stream, tk, ik, wIn2, Ivec);
    hipLaunchKernelGGL(prep_emis, dim3((100*SP + 255)/256), dim3(256), 0, stream, ek, emisP);
    hipLaunchKernelGGL(extract_obs, dim3((NB*TT + 3)/4), dim3(256), 0, stream, x, obs);
    hipLaunchKernelGGL(forward, dim3(NB), dim3(64), 0, stream,
                       emisP, (const float4*)wIn2, Ivec, obs, out);
}

// Round 11
// 915.888 us; speedup vs baseline: 2.2278x; 1.0594x over previous
//
#include <hip/hip_runtime.h>
#include <math.h>

#pragma clang fp contract(fast)

#define S    612
#define TT   8192
#define NB   32
#define SPE  768          // emission row stride in floats (12 per lane, 16B aligned)

typedef float v2f __attribute__((ext_vector_type(2)));

// workspace layout (bytes)
#define WIN_OFF   0        // 640 float4 = 10240 B
#define IV_OFF    10240    // 4 floats
#define EMIS_OFF  16384    // 100*768 floats = 307200 B (pair-reordered, 12/lane)
#define OBS_OFF   327680   // 32*8192 ints = 1 MB

__global__ __launch_bounds__(256) void prep_tables(
    const float* __restrict__ tk, const float* __restrict__ ik,
    float* __restrict__ wIn2, float* __restrict__ Ivec)
{
    int i = blockIdx.x * 256 + threadIdx.x;
    if (i < S) {
        float l0 = tk[3*i], l1 = tk[3*i+1], l2 = tk[3*i+2], l3 = 1.0f;
        float m = fmaxf(fmaxf(l0, l1), fmaxf(l2, l3));
        float e0 = expf(l0-m), e1 = expf(l1-m), e2 = expf(l2-m), e3 = expf(l3-m);
        float inv = 1.0f / (e0+e1+e2+e3);
        wIn2[4*i + 0]              = e0*inv;
        wIn2[4*((i+1)%S) + 1]      = e1*inv;
        wIn2[4*((i+2)%S) + 2]      = e2*inv;
        wIn2[4*((i+3)%S) + 3]      = e3*inv;
    } else if (i < 640) {
        wIn2[4*i+0] = 0.f; wIn2[4*i+1] = 0.f; wIn2[4*i+2] = 0.f; wIn2[4*i+3] = 0.f;
    } else if (i == 640) {
        float l0 = ik[0], l1 = ik[1], l2 = ik[2], l3 = ik[3];
        float m = fmaxf(fmaxf(l0,l1), fmaxf(l2,l3));
        float e0 = expf(l0-m), e1 = expf(l1-m), e2 = expf(l2-m), e3 = expf(l3-m);
        float inv = 1.0f / (e0+e1+e2+e3);
        Ivec[0]=e0*inv; Ivec[1]=e1*inv; Ivec[2]=e2*inv; Ivec[3]=e3*inv;
    }
}

// emission table, stride-5 pair-reordered, 12 floats per lane (pads 10,11 = 0):
// row o, lane ln: float idx 2k   = e[state 10ln+k]   (k=0..4)
//                 float idx 2k+1 = e[state 10ln+k+5]
__global__ __launch_bounds__(256) void prep_emis(
    const float* __restrict__ ek, float* __restrict__ emisP)
{
    int tid = blockIdx.x * 256 + threadIdx.x;       // tid = o*768 + q
    if (tid >= 100*SPE) return;
    int q = tid % SPE;
    int o = tid / SPE;
    int ln = q / 12, idx = q % 12;
    float val = 0.0f;
    if (ln < 62 && idx < 10) {
        int j = (idx & 1) ? 5 + (idx >> 1) : (idx >> 1);
        int s = ln*10 + j;
        if (s < S-1) {
            int c = o >> 2, le = o & 3;
            if (c == 0) {
                val = 0.25f;
            } else {
                const float* g = ek + s*96 + (c-1)*4;
                float a0=g[0], a1=g[1], a2=g[2], a3=g[3];
                float m = fmaxf(fmaxf(a0,a1), fmaxf(a2,a3));
                float x0=expf(a0-m), x1=expf(a1-m), x2=expf(a2-m), x3=expf(a3-m);
                float inv = 1.0f/(x0+x1+x2+x3);
                float sel = (le==0)?x0:(le==1)?x1:(le==2)?x2:x3;
                val = sel * inv;
            }
        }
    }
    emisP[tid] = val;
}

__global__ __launch_bounds__(256) void extract_obs(
    const float* __restrict__ x, int* __restrict__ obs)
{
    int row  = blockIdx.x * 4 + (threadIdx.x >> 6);
    int lane = threadIdx.x & 63;
    if (row >= NB*TT) return;
    const float* r = x + (size_t)row * 101;
    float acc = r[lane] * (float)lane;
    if (lane < 37) acc += r[64 + lane] * (float)(64 + lane);
    #pragma unroll
    for (int m = 32; m >= 1; m >>= 1) acc += __shfl_xor(acc, m, 64);
    if (lane == 0) obs[row] = (int)(acc + 0.5f);
}

// lane-shift-up-by-1 via DPP wave_shr:1 (VALU pipe); lane 0 -> 0
__device__ __forceinline__ float dpp_up1(float x) {
    int xi = __builtin_bit_cast(int, x);
    int r = __builtin_amdgcn_update_dpp(0, xi, 0x138, 0xF, 0xF, true);
    return __builtin_bit_cast(float, r);
}
template<int CTRL>
__device__ __forceinline__ float dpp_add(float x) {
    int sh = __builtin_amdgcn_update_dpp(0, __builtin_bit_cast(int, x), CTRL, 0xF, 0xF, true);
    return x + __builtin_bit_cast(float, sh);
}
__device__ __forceinline__ float rdlanef(float x, int lane) {
    return __builtin_bit_cast(float, __builtin_amdgcn_readlane(__builtin_bit_cast(int, x), lane));
}

// one HMM step, stride-5 pairs p[j] = (a_j, a_{j+5}); E0..E4 emission pairs.
#define HMM_COREP(E0,E1,E2,E3,E4)                                            \
  {                                                                          \
    float pm1 = dpp_up1(p[4].y);                                             \
    float pm2 = dpp_up1(p[3].y);                                             \
    float pm3 = dpp_up1(p[2].y);                                             \
    float v609 = rdlanef(p[4].y, 60);                                        \
    float v610 = rdlanef(p[0].x, 61);                                        \
    float v611 = rdlanef(p[1].x, 61);                                        \
    pm1 = isl0 ? v611 : pm1;                                                 \
    pm2 = isl0 ? v610 : pm2;                                                 \
    pm3 = isl0 ? v609 : pm3;                                                 \
    v2f B1; B1.x = pm1; B1.y = p[4].x;                                       \
    v2f B2; B2.x = pm2; B2.y = p[3].x;                                       \
    v2f B3; B3.x = pm3; B3.y = p[2].x;                                       \
    v2f c0 = p[0]*W[0][0] + B1*W[0][1]   + B2*W[0][2]   + B3*W[0][3];        \
    v2f c1 = p[1]*W[1][0] + p[0]*W[1][1] + B1*W[1][2]   + B2*W[1][3];        \
    v2f c2 = p[2]*W[2][0] + p[1]*W[2][1] + p[0]*W[2][2] + B1*W[2][3];        \
    v2f c3 = p[3]*W[3][0] + p[2]*W[3][1] + p[1]*W[3][2] + p[0]*W[3][3];      \
    v2f c4 = p[4]*W[4][0] + p[3]*W[4][1] + p[2]*W[4][2] + p[1]*W[4][3];      \
    p[0] = c0*(E0); p[1] = c1*(E1); p[2] = c2*(E2);                          \
    p[3] = c3*(E3); p[4] = c4*(E4);                                          \
  }

#define HMM_STEPP(JB) HMM_COREP(eb[JB][0],eb[JB][1],eb[JB][2],eb[JB][3],eb[JB][4])

// refill buffer JB with (pair-reordered) emission row for obs OV; 3 wide loads
#define PREFETCH(JB, OV)                                                     \
  { int _oo = __builtin_amdgcn_readfirstlane(OV);                            \
    const float* _pp = emisP + (size_t)_oo*SPE + 12*l;                       \
    float4 _q0 = *(const float4*)_pp;                                        \
    float4 _q1 = *(const float4*)(_pp+4);                                    \
    float2 _q2 = *(const float2*)(_pp+8);                                    \
    eb[JB][0] = (v2f){_q0.x,_q0.y}; eb[JB][1] = (v2f){_q0.z,_q0.w};          \
    eb[JB][2] = (v2f){_q1.x,_q1.y}; eb[JB][3] = (v2f){_q1.z,_q1.w};          \
    eb[JB][4] = (v2f){_q2.x,_q2.y}; }

#define STEPJ(JB, OV)  HMM_STEPP(JB); PREFETCH(JB, OV);

#define LOCSUM() (((p[0].x+p[0].y)+(p[1].x+p[1].y)) +                        \
                  ((p[2].x+p[2].y)+(p[3].x+p[3].y)) + (p[4].x+p[4].y))

// 16-step renorm block (steps t0..t0+15, t0 mult of 16); buffer id = t&7.
// Refills: step j targets t0+j+8 -> obs C2.x..N1.w = obs[t0+8 .. t0+23].
// z (sum at end of previous block) reduced via 6 DPP stages, folded at j=15.
#define GROUP16(C2,C3,N0,N1)                                                 \
    STEPJ(0, (C2).x); zl = dpp_add<0x111>(zl);                               \
    STEPJ(1, (C2).y); zl = dpp_add<0x112>(zl);                               \
    STEPJ(2, (C2).z); zl = dpp_add<0x114>(zl);                               \
    STEPJ(3, (C2).w); zl = dpp_add<0x118>(zl);                               \
    STEPJ(4, (C3).x); zl = dpp_add<0x142>(zl);                               \
    STEPJ(5, (C3).y); zl = dpp_add<0x143>(zl);                               \
    STEPJ(6, (C3).z);                                                        \
    STEPJ(7, (C3).w);                                                        \
    STEPJ(0, (N0).x);                                                        \
    STEPJ(1, (N0).y);                                                        \
    STEPJ(2, (N0).z);                                                        \
    STEPJ(3, (N0).w);                                                        \
    STEPJ(4, (N1).x);                                                        \
    {                                                                        \
      float z    = rdlanef(zl, 63);                                          \
      float inv_ = __builtin_amdgcn_rcpf(z);                                 \
      float lg_  = __logf(z);                                                \
      STEPJ(5, (N1).y);                                                      \
      STEPJ(6, (N1).z);                                                      \
      v2f ivP; ivP.x = inv_; ivP.y = inv_;                                   \
      v2f ep0=eb[7][0]*ivP, ep1=eb[7][1]*ivP, ep2=eb[7][2]*ivP;              \
      v2f ep3=eb[7][3]*ivP, ep4=eb[7][4]*ivP;                                \
      HMM_COREP(ep0,ep1,ep2,ep3,ep4);                                        \
      PREFETCH(7, (N1).w);                                                   \
      ll += lg_;                                                             \
    }                                                                        \
    zl = LOCSUM();

// one wave per batch; no LDS; obs via uniform int4 blocks (scalar loads)
__global__ __launch_bounds__(64) void forward(
    const float* __restrict__ emisP, const float4* __restrict__ wIn2,
    const float* __restrict__ Ivec, const int* __restrict__ obs,
    float* __restrict__ out)
{
    const int l = threadIdx.x;
    const int b = blockIdx.x;
    const bool isl0 = (l == 0);
    const int* obp = obs + b * TT;

    // per-lane incoming weights, stride-5 pairs
    v2f W[5][4];
    {
        float4 w[10];
        #pragma unroll
        for (int k = 0; k < 10; ++k) w[k] = wIn2[10*l + k];
        #pragma unroll
        for (int j = 0; j < 5; ++j) {
            W[j][0].x = w[j].x; W[j][0].y = w[j+5].x;
            W[j][1].x = w[j].y; W[j][1].y = w[j+5].y;
            W[j][2].x = w[j].z; W[j][2].y = w[j+5].z;
            W[j][3].x = w[j].w; W[j][3].y = w[j+5].w;
        }
    }

    // obs blocks (uniform -> scalar regs): cur = obs[0..15], nxt = obs[16..31]
    int4 c0, c1, c2, c3, n0_, n1_, n2_, n3_;
    {
        const int4* o4 = (const int4*)obp;
        c0 = o4[0]; c1 = o4[1]; c2 = o4[2]; c3 = o4[3];
        n0_ = o4[4]; n1_ = o4[5]; n2_ = o4[6]; n3_ = o4[7];
    }

    v2f p[5];
    float ll = 0.0f;
    v2f eb[8][5];

    // t = 0: states 0..3 (lane 0) get I * emission
    {
        int o0 = __builtin_amdgcn_readfirstlane(c0.x);
        const float* ep = emisP + (size_t)o0*SPE + 12*l;
        float e0 = ep[0], e1 = ep[2], e2 = ep[4], e3 = ep[6];
        p[0].x = isl0 ? e0*Ivec[0] : 0.f;  p[0].y = 0.f;
        p[1].x = isl0 ? e1*Ivec[1] : 0.f;  p[1].y = 0.f;
        p[2].x = isl0 ? e2*Ivec[2] : 0.f;  p[2].y = 0.f;
        p[3].x = isl0 ? e3*Ivec[3] : 0.f;  p[3].y = 0.f;
        p[4].x = 0.f; p[4].y = 0.f;
    }
    float zl = LOCSUM();   // z_0 partial; DPP tree runs inside the prologue

    // initial buffers for t = 1..8 (ids 1..7,0)
    PREFETCH(1, c0.y); PREFETCH(2, c0.z); PREFETCH(3, c0.w);
    PREFETCH(4, c1.x); PREFETCH(5, c1.y); PREFETCH(6, c1.z); PREFETCH(7, c1.w);
    PREFETCH(0, c2.x);

    // prologue: steps t = 1..15 (fold at t=15)
    STEPJ(1, c2.y); zl = dpp_add<0x111>(zl);
    STEPJ(2, c2.z); zl = dpp_add<0x112>(zl);
    STEPJ(3, c2.w); zl = dpp_add<0x114>(zl);
    STEPJ(4, c3.x); zl = dpp_add<0x118>(zl);
    STEPJ(5, c3.y); zl = dpp_add<0x142>(zl);
    STEPJ(6, c3.z); zl = dpp_add<0x143>(zl);
    STEPJ(7, c3.w);
    STEPJ(0, n0_.x);
    STEPJ(1, n0_.y);
    STEPJ(2, n0_.z);
    STEPJ(3, n0_.w);
    STEPJ(4, n1_.x);
    {
      float z    = rdlanef(zl, 63);
      float inv_ = __builtin_amdgcn_rcpf(z);
      float lg_  = __logf(z);
      STEPJ(5, n1_.y);
      STEPJ(6, n1_.z);
      v2f ivP; ivP.x = inv_; ivP.y = inv_;
      v2f ep0=eb[7][0]*ivP, ep1=eb[7][1]*ivP, ep2=eb[7][2]*ivP;
      v2f ep3=eb[7][3]*ivP, ep4=eb[7][4]*ivP;
      HMM_COREP(ep0,ep1,ep2,ep3,ep4);
      PREFETCH(7, n1_.w);
      ll += lg_;
    }
    zl = LOCSUM();

    // main: 511 blocks of 16 steps (t = 16..8191)
    #pragma unroll 1
    for (int g = 1; g < 512; ++g) {
        c2 = n2_; c3 = n3_;
        const int4* o4n = (const int4*)(obp + ((g < 511) ? (g+1)*16 : 8176));
        n0_ = o4n[0]; n1_ = o4n[1]; n2_ = o4n[2]; n3_ = o4n[3];
        GROUP16(c2, c3, n0_, n1_);
    }

    // final: z for the last (un-logged) step
    {
        float zf = zl;
        zf = dpp_add<0x111>(zf);
        zf = dpp_add<0x112>(zf);
        zf = dpp_add<0x114>(zf);
        zf = dpp_add<0x118>(zf);
        zf = dpp_add<0x142>(zf);
        zf = dpp_add<0x143>(zf);
        ll += __logf(rdlanef(zf, 63));
    }
    if (isl0) out[b] = ll;
}

extern "C" void kernel_launch(void* const* d_in, const int* in_sizes, int n_in,
                              void* d_out, int out_size, void* d_ws, size_t ws_size,
                              hipStream_t stream)
{
    const float* x  = (const float*)d_in[0];   // inputs [32,8192,101]
    const float* ik = (const float*)d_in[1];   // init_kernel [4]
    const float* tk = (const float*)d_in[2];   // transition_kernel [1836]
    const float* ek = (const float*)d_in[3];   // emission_kernel [58656]
    float* out = (float*)d_out;

    char* ws = (char*)d_ws;
    float*  wIn2  = (float*)(ws + WIN_OFF);
    float*  Ivec  = (float*)(ws + IV_OFF);
    float*  emisP = (float*)(ws + EMIS_OFF);
    int*    obs   = (int*)(ws + OBS_OFF);

    hipLaunchKernelGGL(prep_tables, dim3(3), dim3(256), 0, stream, tk, ik, wIn2, Ivec);
    hipLaunchKernelGGL(prep_emis, dim3((100*SPE + 255)/256), dim3(256), 0, stream, ek, emisP);
    hipLaunchKernelGGL(extract_obs, dim3((NB*TT + 3)/4), dim3(256), 0, stream, x, obs);
    hipLaunchKernelGGL(forward, dim3(NB), dim3(64), 0, stream,
                       emisP, (const float4*)wIn2, Ivec, obs, out);
}